// Round 1
// baseline (27.431 us; speedup 1.0000x reference)
//
#include <hip/hip_runtime.h>

// Problem constants (from reference): B=8, A=9, H=56, W=56, N=64
#define BB 8
#define AA 9
#define HH 56
#define WW 56
#define NN 64

constexpr int P  = AA * HH * WW;   // 28224 proposals per batch image
constexpr int NP = BB * P;         // 225792 total proposals

// Kernel A: proposals[b][a][h][w][4]
//   cx = grid_x + off0 ; cy = grid_y + off1
//   w  = anc_w * exp(off2) ; h = anc_h * exp(off3)
//   out = [cx - w/2, cy - h/2, cx + w/2, cy + h/2]
__global__ void proposals_kernel(const float* __restrict__ anc,
                                 const float* __restrict__ grid,
                                 const float* __restrict__ offsets,
                                 float* __restrict__ out) {
    int tid = blockIdx.x * blockDim.x + threadIdx.x;
    if (tid >= NP) return;

    int w_ = tid % WW;
    int t  = tid / WW;
    int h_ = t % HH;
    t /= HH;
    int a = t % AA;
    int b = t / AA;

    int gidx = (b * HH + h_) * WW + w_;
    float x = grid[gidx * 2 + 0];
    float y = grid[gidx * 2 + 1];
    float aw = anc[a * 2 + 0];
    float ah = anc[a * 2 + 1];

    float4 off = reinterpret_cast<const float4*>(offsets)[tid];

    float cx = x + off.x;
    float cy = y + off.y;
    float pw = aw * expf(off.z);
    float ph = ah * expf(off.w);

    float4 pr;
    pr.x = cx - 0.5f * pw;
    pr.y = cy - 0.5f * ph;
    pr.z = cx + 0.5f * pw;
    pr.w = cy + 0.5f * ph;
    reinterpret_cast<float4*>(out)[tid] = pr;
}

// Kernel B: iou[b][p][n] for one proposal x 4 consecutive bboxes per thread.
// Writes are float4, fully coalesced across the wave.
__global__ void iou_kernel(const float* __restrict__ proposals,
                           const float* __restrict__ bboxes,
                           float* __restrict__ iou) {
    int tid = blockIdx.x * blockDim.x + threadIdx.x;
    if (tid >= NP * (NN / 4)) return;

    int n4 = tid & (NN / 4 - 1);   // which group of 4 bboxes (0..15)
    int t  = tid >> 4;             // b*P + p
    int b  = t / P;

    float4 pr = reinterpret_cast<const float4*>(proposals)[t];
    float pa = (pr.z - pr.x) * (pr.w - pr.y);

    float4 res;
    float r[4];
    #pragma unroll
    for (int i = 0; i < 4; ++i) {
        int n = n4 * 4 + i;
        const float* bb = bboxes + (size_t)(b * NN + n) * 5;
        float b0 = bb[0], b1 = bb[1], b2 = bb[2], b3 = bb[3];
        float ba = (b2 - b0) * (b3 - b1);
        float mx0 = fmaxf(pr.x, b0);
        float mx1 = fmaxf(pr.y, b1);
        float mn2 = fminf(pr.z, b2);
        float mn3 = fminf(pr.w, b3);
        float iw = fmaxf(mn2 - mx0, 0.0f);
        float ih = fmaxf(mn3 - mx1, 0.0f);
        float inter = iw * ih;
        r[i] = inter / (pa + ba - inter);
    }
    res.x = r[0]; res.y = r[1]; res.z = r[2]; res.w = r[3];
    reinterpret_cast<float4*>(iou)[tid] = res;
}

extern "C" void kernel_launch(void* const* d_in, const int* in_sizes, int n_in,
                              void* d_out, int out_size, void* d_ws, size_t ws_size,
                              hipStream_t stream) {
    const float* anc     = (const float*)d_in[0];  // (9, 2)
    const float* grid    = (const float*)d_in[1];  // (8, 56, 56, 2)
    const float* offsets = (const float*)d_in[2];  // (8, 9, 56, 56, 4)
    const float* bboxes  = (const float*)d_in[3];  // (8, 64, 5)

    float* out_proposals = (float*)d_out;                  // 903168 floats
    float* out_iou       = (float*)d_out + (size_t)NP * 4; // 14450688 floats

    {
        int threads = NP;
        int block = 256;
        int gridsz = (threads + block - 1) / block;
        proposals_kernel<<<gridsz, block, 0, stream>>>(anc, grid, offsets, out_proposals);
    }
    {
        int threads = NP * (NN / 4);
        int block = 256;
        int gridsz = (threads + block - 1) / block;
        iou_kernel<<<gridsz, block, 0, stream>>>(out_proposals, bboxes, out_iou);
    }
}

// Round 2
// 17.734 us; speedup vs baseline: 1.5468x; 1.5468x over previous
//
#include <hip/hip_runtime.h>

// Problem constants (from reference): B=8, A=9, H=56, W=56, N=64
#define BB 8
#define AA 9
#define HH 56
#define WW 56
#define NN 64

constexpr int P   = AA * HH * WW;  // 28224 proposals per batch image
constexpr int HW  = HH * WW;       // 3136
constexpr int BLK = 256;
constexpr int PBLK = (P + BLK - 1) / BLK;  // 111 blocks per batch image

// Fused: proposals + IoU in one kernel.
// Block handles 256 consecutive proposals of one batch image.
// Phase 1: each thread computes 1 proposal -> LDS + global (coalesced float4).
// Phase 2: each thread owns 4 bboxes IN REGISTERS (n4 = tid&15 fixed),
//          iterates 16 proposals from LDS (broadcast), writes coalesced float4.
__global__ __launch_bounds__(BLK) void fused_detector_kernel(
    const float* __restrict__ anc,      // (9,2)
    const float* __restrict__ grid,     // (8,56,56,2)
    const float* __restrict__ offsets,  // (8,9,56,56,4)
    const float* __restrict__ bboxes,   // (8,64,5)
    float* __restrict__ out_prop,       // (8,9,56,56,4)
    float* __restrict__ out_iou)        // (8,28224,64)
{
    __shared__ float4 sprop[BLK];

    const int tid = threadIdx.x;
    const int b   = blockIdx.y;
    const int p0  = blockIdx.x * BLK;
    const int p   = p0 + tid;

    // ---- bbox prefetch into registers (independent of phase 1) ----
    const int n4 = tid & 15;             // this thread's bbox group, fixed
    float bx0[4], by0[4], bx1[4], by1[4], bar[4];
    #pragma unroll
    for (int i = 0; i < 4; ++i) {
        const float* bb = bboxes + (size_t)(b * NN + n4 * 4 + i) * 5;
        bx0[i] = bb[0]; by0[i] = bb[1]; bx1[i] = bb[2]; by1[i] = bb[3];
        bar[i] = (bx1[i] - bx0[i]) * (by1[i] - by0[i]);
    }

    // ---- phase 1: proposal ----
    if (p < P) {
        int a  = p / HW;
        int hw = p - a * HW;
        float2 g  = reinterpret_cast<const float2*>(grid)[b * HW + hw];
        float  aw = anc[a * 2 + 0];
        float  ah = anc[a * 2 + 1];
        float4 off = reinterpret_cast<const float4*>(offsets)[(size_t)b * P + p];

        float cx = g.x + off.x;
        float cy = g.y + off.y;
        float pw = aw * __expf(off.z);
        float ph = ah * __expf(off.w);

        float4 pr;
        pr.x = cx - 0.5f * pw;
        pr.y = cy - 0.5f * ph;
        pr.z = cx + 0.5f * pw;
        pr.w = cy + 0.5f * ph;

        sprop[tid] = pr;
        reinterpret_cast<float4*>(out_prop)[(size_t)b * P + p] = pr;
    }
    __syncthreads();

    // ---- phase 2: IoU ----
    const int prb  = tid >> 4;           // proposal sub-index within iteration
    const int pmax = P - p0;             // active local proposals (256, or 64 in tail)
    float4* iou4 = reinterpret_cast<float4*>(out_iou) + ((size_t)b * P + p0) * (NN / 4);

    for (int c = 0; c < 16; ++c) {
        int pl = c * 16 + prb;
        if (pl >= pmax) break;           // wave-uniform (pmax multiple of 16)

        float4 pr = sprop[pl];
        float  pa = (pr.z - pr.x) * (pr.w - pr.y);

        float rv[4];
        #pragma unroll
        for (int i = 0; i < 4; ++i) {
            float mx0 = fmaxf(pr.x, bx0[i]);
            float my0 = fmaxf(pr.y, by0[i]);
            float mn1 = fminf(pr.z, bx1[i]);
            float mn2 = fminf(pr.w, by1[i]);
            float iw  = fmaxf(mn1 - mx0, 0.0f);
            float ih  = fmaxf(mn2 - my0, 0.0f);
            float inter = iw * ih;
            float uni   = pa + bar[i] - inter;
            rv[i] = inter * __builtin_amdgcn_rcpf(uni);
        }
        float4 r;
        r.x = rv[0]; r.y = rv[1]; r.z = rv[2]; r.w = rv[3];
        iou4[c * BLK + tid] = r;
    }
}

extern "C" void kernel_launch(void* const* d_in, const int* in_sizes, int n_in,
                              void* d_out, int out_size, void* d_ws, size_t ws_size,
                              hipStream_t stream) {
    const float* anc     = (const float*)d_in[0];  // (9, 2)
    const float* grid    = (const float*)d_in[1];  // (8, 56, 56, 2)
    const float* offsets = (const float*)d_in[2];  // (8, 9, 56, 56, 4)
    const float* bboxes  = (const float*)d_in[3];  // (8, 64, 5)

    float* out_proposals = (float*)d_out;                        // 903168 floats
    float* out_iou       = (float*)d_out + (size_t)BB * P * 4;   // 14450688 floats

    dim3 gridsz(PBLK, BB);
    fused_detector_kernel<<<gridsz, BLK, 0, stream>>>(
        anc, grid, offsets, bboxes, out_proposals, out_iou);
}

// Round 4
// 17.149 us; speedup vs baseline: 1.5996x; 1.0341x over previous
//
#include <hip/hip_runtime.h>

// Problem constants (from reference): B=8, A=9, H=56, W=56, N=64
#define BB 8
#define AA 9
#define HH 56
#define WW 56
#define NN 64

constexpr int P   = AA * HH * WW;  // 28224 proposals per batch image
constexpr int HW  = HH * WW;       // 3136
constexpr int BLK = 256;
constexpr int PBLK = (P + BLK - 1) / BLK;  // 111 blocks per batch image

// clang-native vector type: __builtin_nontemporal_store accepts these
// (it rejects HIP_vector_type<float,4>).
typedef float f32x4 __attribute__((ext_vector_type(4)));

// Fused: proposals + IoU in one kernel.
// Block handles 256 consecutive proposals of one batch image.
// Phase 1: each thread computes 1 proposal -> LDS + global (coalesced float4, NT).
// Phase 2: each thread owns 4 bboxes IN REGISTERS (n4 = tid&15 fixed),
//          iterates 16 proposals from LDS (broadcast), writes coalesced float4 (NT).
//          Unrolled x2 for store/load ILP.
__global__ __launch_bounds__(BLK) void fused_detector_kernel(
    const float* __restrict__ anc,      // (9,2)
    const float* __restrict__ grid,     // (8,56,56,2)
    const float* __restrict__ offsets,  // (8,9,56,56,4)
    const float* __restrict__ bboxes,   // (8,64,5)
    float* __restrict__ out_prop,       // (8,9,56,56,4)
    float* __restrict__ out_iou)        // (8,28224,64)
{
    __shared__ f32x4 sprop[BLK];

    const int tid = threadIdx.x;
    const int b   = blockIdx.y;
    const int p0  = blockIdx.x * BLK;
    const int p   = p0 + tid;

    // ---- bbox prefetch into registers (independent of phase 1) ----
    const int n4 = tid & 15;             // this thread's bbox group, fixed
    float bx0[4], by0[4], bx1[4], by1[4], bar[4];
    #pragma unroll
    for (int i = 0; i < 4; ++i) {
        const float* bb = bboxes + (size_t)(b * NN + n4 * 4 + i) * 5;
        bx0[i] = bb[0]; by0[i] = bb[1]; bx1[i] = bb[2]; by1[i] = bb[3];
        bar[i] = (bx1[i] - bx0[i]) * (by1[i] - by0[i]);
    }

    // ---- phase 1: proposal ----
    if (p < P) {
        int a  = p / HW;
        int hw = p - a * HW;
        float2 g  = reinterpret_cast<const float2*>(grid)[b * HW + hw];
        float  aw = anc[a * 2 + 0];
        float  ah = anc[a * 2 + 1];
        f32x4 off = reinterpret_cast<const f32x4*>(offsets)[(size_t)b * P + p];

        float cx = g.x + off.x;
        float cy = g.y + off.y;
        float pw = aw * __expf(off.z);
        float ph = ah * __expf(off.w);

        f32x4 pr;
        pr.x = cx - 0.5f * pw;
        pr.y = cy - 0.5f * ph;
        pr.z = cx + 0.5f * pw;
        pr.w = cy + 0.5f * ph;

        sprop[tid] = pr;
        __builtin_nontemporal_store(pr, reinterpret_cast<f32x4*>(out_prop) + (size_t)b * P + p);
    }
    __syncthreads();

    // ---- phase 2: IoU ----
    const int prb  = tid >> 4;           // proposal sub-index within iteration
    const int pmax = P - p0;             // active local proposals (256, or 64 in tail)
    f32x4* iou4 = reinterpret_cast<f32x4*>(out_iou) + ((size_t)b * P + p0) * (NN / 4);

    #pragma unroll 2
    for (int c = 0; c < 16; ++c) {
        int pl = c * 16 + prb;
        if (pl >= pmax) break;           // wave-uniform (pmax multiple of 16)

        f32x4 pr = sprop[pl];
        float pa = (pr.z - pr.x) * (pr.w - pr.y);

        float rv[4];
        #pragma unroll
        for (int i = 0; i < 4; ++i) {
            float mx0 = fmaxf(pr.x, bx0[i]);
            float my0 = fmaxf(pr.y, by0[i]);
            float mn1 = fminf(pr.z, bx1[i]);
            float mn2 = fminf(pr.w, by1[i]);
            float iw  = fmaxf(mn1 - mx0, 0.0f);
            float ih  = fmaxf(mn2 - my0, 0.0f);
            float inter = iw * ih;
            float uni   = pa + bar[i] - inter;
            rv[i] = inter * __builtin_amdgcn_rcpf(uni);
        }
        f32x4 r;
        r.x = rv[0]; r.y = rv[1]; r.z = rv[2]; r.w = rv[3];
        __builtin_nontemporal_store(r, iou4 + c * BLK + tid);
    }
}

extern "C" void kernel_launch(void* const* d_in, const int* in_sizes, int n_in,
                              void* d_out, int out_size, void* d_ws, size_t ws_size,
                              hipStream_t stream) {
    const float* anc     = (const float*)d_in[0];  // (9, 2)
    const float* grid    = (const float*)d_in[1];  // (8, 56, 56, 2)
    const float* offsets = (const float*)d_in[2];  // (8, 9, 56, 56, 4)
    const float* bboxes  = (const float*)d_in[3];  // (8, 64, 5)

    float* out_proposals = (float*)d_out;                        // 903168 floats
    float* out_iou       = (float*)d_out + (size_t)BB * P * 4;   // 14450688 floats

    dim3 gridsz(PBLK, BB);
    fused_detector_kernel<<<gridsz, BLK, 0, stream>>>(
        anc, grid, offsets, bboxes, out_proposals, out_iou);
}

// Round 5
// 16.272 us; speedup vs baseline: 1.6857x; 1.0539x over previous
//
#include <hip/hip_runtime.h>

// Problem constants (from reference): B=8, A=9, H=56, W=56, N=64
#define BB 8
#define AA 9
#define HH 56
#define WW 56
#define NN 64

constexpr int P   = AA * HH * WW;  // 28224 proposals per batch image
constexpr int HW  = HH * WW;       // 3136
constexpr int BLK = 256;
constexpr int PBLK = (P + BLK - 1) / BLK;  // 111 blocks per batch image (110 full + 64-tail)

// clang-native vector type: __builtin_nontemporal_store accepts these
// (it rejects HIP_vector_type<float,4>).
typedef float f32x4 __attribute__((ext_vector_type(4)));

// Fused proposals + IoU, barrier-free:
// Phase 1: thread computes 1 proposal -> LDS + global (NT float4).
// Phase 2: WAVE-LOCAL — wave w consumes only proposals [64w, 64w+64) that it
//          computed itself, so no __syncthreads is needed (within-wave LDS
//          ordering handled by lgkmcnt). Each thread owns 4 bboxes in
//          registers (n4 = tid&15), fully unrolled 16 iterations, one
//          coalesced NT float4 store each (1 KB/wave contiguous).
__global__ __launch_bounds__(BLK) void fused_detector_kernel(
    const float* __restrict__ anc,      // (9,2)
    const float* __restrict__ grid,     // (8,56,56,2)
    const float* __restrict__ offsets,  // (8,9,56,56,4)
    const float* __restrict__ bboxes,   // (8,64,5)
    float* __restrict__ out_prop,       // (8,9,56,56,4)
    float* __restrict__ out_iou)        // (8,28224,64)
{
    __shared__ f32x4 sprop[BLK];

    const int tid = threadIdx.x;
    const int b   = blockIdx.y;
    const int p0  = blockIdx.x * BLK;
    const int p   = p0 + tid;
    const bool active = (p < P);

    // ---- issue the long-latency offsets load FIRST ----
    f32x4 off = {0.f, 0.f, 0.f, 0.f};
    if (active) off = reinterpret_cast<const f32x4*>(offsets)[(size_t)b * P + p];

    // ---- bbox prefetch into registers ----
    const int n4 = tid & 15;             // this thread's bbox group, fixed
    float bx0[4], by0[4], bx1[4], by1[4], bar[4];
    #pragma unroll
    for (int i = 0; i < 4; ++i) {
        const float* bb = bboxes + (size_t)(b * NN + n4 * 4 + i) * 5;
        bx0[i] = bb[0]; by0[i] = bb[1]; bx1[i] = bb[2]; by1[i] = bb[3];
        bar[i] = (bx1[i] - bx0[i]) * (by1[i] - by0[i]);
    }

    // ---- phase 1: proposal ----
    if (active) {
        int a  = p / HW;
        int hw = p - a * HW;
        float2 g  = reinterpret_cast<const float2*>(grid)[b * HW + hw];
        float  aw = anc[a * 2 + 0];
        float  ah = anc[a * 2 + 1];

        float cx = g.x + off.x;
        float cy = g.y + off.y;
        float pw = aw * __expf(off.z);
        float ph = ah * __expf(off.w);

        f32x4 pr;
        pr.x = cx - 0.5f * pw;
        pr.y = cy - 0.5f * ph;
        pr.z = cx + 0.5f * pw;
        pr.w = cy + 0.5f * ph;

        sprop[tid] = pr;
        __builtin_nontemporal_store(pr, reinterpret_cast<f32x4*>(out_prop) + (size_t)b * P + p);
    }
    // NO __syncthreads: phase 2 is wave-local (reads only this wave's sprop).

    // ---- phase 2: IoU (wave-local) ----
    const int w   = tid >> 6;            // wave index within block
    const int sub = (tid >> 4) & 3;      // proposal sub-index within iteration

    if (p0 + w * 64 < P) {               // wave-uniform guard (tail: only wave 0 active)
        f32x4* iou4 = reinterpret_cast<f32x4*>(out_iou) + ((size_t)b * P + p0) * (NN / 4);

        #pragma unroll
        for (int c = 0; c < 16; ++c) {
            const int pl = w * 64 + c * 4 + sub;   // this wave's own proposals
            f32x4 pr = sprop[pl];
            float pa = (pr.z - pr.x) * (pr.w - pr.y);

            float rv[4];
            #pragma unroll
            for (int i = 0; i < 4; ++i) {
                float mx0 = fmaxf(pr.x, bx0[i]);
                float my0 = fmaxf(pr.y, by0[i]);
                float mn1 = fminf(pr.z, bx1[i]);
                float mn2 = fminf(pr.w, by1[i]);
                float iw  = fmaxf(mn1 - mx0, 0.0f);
                float ih  = fmaxf(mn2 - my0, 0.0f);
                float inter = iw * ih;
                float uni   = pa + bar[i] - inter;
                rv[i] = inter * __builtin_amdgcn_rcpf(uni);
            }
            f32x4 r;
            r.x = rv[0]; r.y = rv[1]; r.z = rv[2]; r.w = rv[3];
            __builtin_nontemporal_store(r, iou4 + (size_t)pl * (NN / 4) + n4);
        }
    }
}

extern "C" void kernel_launch(void* const* d_in, const int* in_sizes, int n_in,
                              void* d_out, int out_size, void* d_ws, size_t ws_size,
                              hipStream_t stream) {
    const float* anc     = (const float*)d_in[0];  // (9, 2)
    const float* grid    = (const float*)d_in[1];  // (8, 56, 56, 2)
    const float* offsets = (const float*)d_in[2];  // (8, 9, 56, 56, 4)
    const float* bboxes  = (const float*)d_in[3];  // (8, 64, 5)

    float* out_proposals = (float*)d_out;                        // 903168 floats
    float* out_iou       = (float*)d_out + (size_t)BB * P * 4;   // 14450688 floats

    dim3 gridsz(PBLK, BB);
    fused_detector_kernel<<<gridsz, BLK, 0, stream>>>(
        anc, grid, offsets, bboxes, out_proposals, out_iou);
}